// Round 2
// baseline (404.699 us; speedup 1.0000x reference)
//
#include <hip/hip_runtime.h>
#include <hip/hip_bf16.h>
#include <math.h>

#define H_ 8
#define DK_ 32
#define B_ 4
#define M_ 64
#define N_ 512
#define D_ 256
#define F_ 1024

static constexpr float SCALE = 0.17677669529663687f; // 1/sqrt(32)
static constexpr float EPS = 1e-5f;

typedef __bf16 bf16x8 __attribute__((ext_vector_type(8)));
typedef float f32x4 __attribute__((ext_vector_type(4)));

__device__ inline float bfbits2f(unsigned int b) {
    union { unsigned int i; float f; } c; c.i = b << 16; return c.f;
}

// ---------------- mask dtype detection (uint8 vs int32 bools) ----------------
__global__ __launch_bounds__(256) void detect_kernel(const unsigned int* __restrict__ mask,
                                                     int* __restrict__ flags) {
    __shared__ int s2[256];
    int t = threadIdx.x;
    int cgt = 0;
    for (int i = 0; i < 128; ++i) {
        unsigned int w = mask[t * 128 + i];
        if (w > 1u) cgt++;
    }
    s2[t] = cgt;
    __syncthreads();
    if (t == 0) {
        int b = 0;
        for (int i = 0; i < 256; ++i) b += s2[i];
        flags[1] = (b > 0) ? 1 : 0;
    }
}

// ---------------- tiled weight transpose+convert: dst[n*K+k] = bf16(src[k*N+n]) ----------------
struct TTArgs {
    const void* src[9];
    void* dst[9];
    int tcum[9];   // cumulative 64x64 tile counts
    int kl[9];     // log2 K
    int nl[9];     // log2 N
};

__global__ __launch_bounds__(256) void prep_transpose(TTArgs a) {
    __shared__ float ld[64][65];
    int bx = blockIdx.x;
    int ti = 0;
    while (bx >= a.tcum[ti]) ti++;
    int j = bx - (ti ? a.tcum[ti - 1] : 0);
    int K = 1 << a.kl[ti], N = 1 << a.nl[ti];
    int ntn = N >> 6;
    int kt = j / ntn, nt = j - kt * ntn;
    const float* src = (const float*)a.src[ti];
    __hip_bfloat16* dst = (__hip_bfloat16*)a.dst[ti];
    int t = threadIdx.x;
    int col = t & 63, r0 = t >> 6;
#pragma unroll
    for (int i = 0; i < 16; ++i) {
        int r = i * 4 + r0;
        ld[r][col] = src[(size_t)(kt * 64 + r) * N + nt * 64 + col];
    }
    __syncthreads();
#pragma unroll
    for (int i = 0; i < 16; ++i) {
        int r = i * 4 + r0;
        dst[(size_t)(nt * 64 + r) * K + kt * 64 + col] = __float2bfloat16(ld[col][r]);
    }
}

__global__ __launch_bounds__(256) void prep_bias(const float* bq, const float* bks,
                                                 const float* bvs, const float* bk,
                                                 const float* bv,
                                                 float* bqksvs, float* bkv) {
    int t = threadIdx.x;
    bqksvs[t] = bq[t];
    bqksvs[256 + t] = bks[t];
    bqksvs[512 + t] = bvs[t];
    bkv[t] = bk[t];
    bkv[256 + t] = bv[t];
}

// ---------------- block reduce (256 threads = 4 waves) ----------------
__device__ inline float block_reduce256(float v, bool is_max, float* sbuf) {
#pragma unroll
    for (int off = 32; off > 0; off >>= 1) {
        float o = __shfl_down(v, off, 64);
        v = is_max ? fmaxf(v, o) : (v + o);
    }
    int lane = threadIdx.x & 63, wid = threadIdx.x >> 6;
    if (lane == 0) sbuf[wid] = v;
    __syncthreads();
    float r;
    if (is_max) r = fmaxf(fmaxf(sbuf[0], sbuf[1]), fmaxf(sbuf[2], sbuf[3]));
    else        r = sbuf[0] + sbuf[1] + sbuf[2] + sbuf[3];
    __syncthreads();
    return r;
}

// ---------------- LayerNorm: fp32 in -> bf16 out ----------------
__global__ __launch_bounds__(256) void ln_kernel(const float* __restrict__ xin,
                                                 const float* __restrict__ g,
                                                 const float* __restrict__ bta,
                                                 __hip_bfloat16* __restrict__ out) {
    __shared__ float sbuf[4];
    int row = blockIdx.x, d = threadIdx.x;
    size_t idx = (size_t)row * 256 + d;
    float x = xin[idx];
    float s  = block_reduce256(x, false, sbuf);
    float ss = block_reduce256(x * x, false, sbuf);
    float mu = s * (1.f / 256.f);
    float var = ss * (1.f / 256.f) - mu * mu;
    float y = (x - mu) * rsqrtf(var + EPS) * g[d] + bta[d];
    out[idx] = __float2bfloat16(y);
}

// ---------------- generic MFMA GEMM: out(M,ldc) = A(M,K) @ BT(N,K)^T + bias ----------------
// flags: 1=relu, 4=resid f32, 8=out f32 (else bf16)
__global__ __launch_bounds__(256) void gemm64(const __hip_bfloat16* __restrict__ A,
                                              const __hip_bfloat16* __restrict__ BT,
                                              const float* __restrict__ bias,
                                              const float* __restrict__ resid,
                                              void* __restrict__ out,
                                              int K, int ldc, int flags) {
    __shared__ __align__(16) __bf16 As[64 * 40];
    __shared__ __align__(16) __bf16 Bs[64 * 40];
    const int rowBase = blockIdx.x * 64;
    const int colBase = blockIdx.y * 64;
    const int t = threadIdx.x;
    const int w = t >> 6;
    const int l = t & 63;
    const int lrow = l & 15;
    const int lk8 = (l >> 4) * 8;
    const int ar = t >> 2;
    const int ac = (t & 3) * 8;

    f32x4 acc[4] = {};
    for (int k0 = 0; k0 < K; k0 += 32) {
        bf16x8 av = *(const bf16x8*)(A + (size_t)(rowBase + ar) * K + k0 + ac);
        bf16x8 bv = *(const bf16x8*)(BT + (size_t)(colBase + ar) * K + k0 + ac);
        __syncthreads();
        *(bf16x8*)(As + ar * 40 + ac) = av;
        *(bf16x8*)(Bs + ar * 40 + ac) = bv;
        __syncthreads();
        bf16x8 af = *(const bf16x8*)(As + (w * 16 + lrow) * 40 + lk8);
#pragma unroll
        for (int c = 0; c < 4; ++c) {
            bf16x8 bf = *(const bf16x8*)(Bs + (c * 16 + lrow) * 40 + lk8);
            acc[c] = __builtin_amdgcn_mfma_f32_16x16x32_bf16(af, bf, acc[c], 0, 0, 0);
        }
    }
    int rbase = rowBase + w * 16 + ((l >> 4) * 4);
#pragma unroll
    for (int c = 0; c < 4; ++c) {
        int col = colBase + c * 16 + (l & 15);
        float bb = bias[col];
#pragma unroll
        for (int r = 0; r < 4; ++r) {
            int row = rbase + r;
            size_t oi = (size_t)row * ldc + col;
            float v = acc[c][r] + bb;
            if (flags & 1) v = fmaxf(v, 0.f);
            if (flags & 4) v += resid[oi];
            if (flags & 8) ((float*)out)[oi] = v;
            else ((__hip_bfloat16*)out)[oi] = __float2bfloat16(v);
        }
    }
}

// ---------------- edge flash: one block per (b, m, n-quarter of 128).
// Barrier-free reg-fragment GEMM  e[64n x 256d] = edge_emb[b, ns.., m, :] @ We,
// fused masked scores (q+e)(k+e) via shfl butterfly, online softmax,
// unnormalized PV accumulation of a*(e+v). Writes per-quarter partials (M, L, PV).
//
// MFMA layout convention (same as verified gemm64/edge_gemm4):
//   acc[rr][c][r] = C[n_row = rr*16 + lh*4 + r][col = w*64 + c*16 + l15]
//   head h = 2w + (c>>1),  dk = (c&1)*16 + l15
__global__ __launch_bounds__(256) void edge_flash(const float* __restrict__ E,
                                                  const __hip_bfloat16* __restrict__ WeT,
                                                  const float* __restrict__ be,
                                                  const __hip_bfloat16* __restrict__ qkvs,
                                                  const __hip_bfloat16* __restrict__ kov,
                                                  const void* __restrict__ mask,
                                                  const int* __restrict__ flags,
                                                  float* __restrict__ fPV,
                                                  float* __restrict__ fML) {
    __shared__ float mbias[128];
    const int bid = blockIdx.x;          // ((b*4 + q)*64 + m) : consecutive blocks share (b,q)
    const int b  = bid >> 8;
    const int qq = (bid >> 6) & 3;
    const int m  = bid & 63;
    const int n0 = qq * 128;
    const int t = threadIdx.x;
    const int w = t >> 6;
    const int l = t & 63;
    const int l15 = l & 15;
    const int lh  = l >> 4;

    if (t < 128) {
        int n = n0 + t;
        int mi = (b * 512 + n) * 64 + m;
        int mk = (flags[1] != 0) ? (int)((const unsigned char*)mask)[mi]
                                 : ((const int*)mask)[mi];
        mbias[t] = mk ? 0.f : -1e30f;
    }

    int   col[4];
    float qv[4], bev[4];
#pragma unroll
    for (int c = 0; c < 4; ++c) {
        col[c] = w * 64 + c * 16 + l15;
        qv[c]  = __bfloat162float(qkvs[(size_t)(b * 64 + m) * 768 + col[c]]);
        bev[c] = be[col[c]];
    }
    const __hip_bfloat16* kvb = kov + (size_t)b * 512 * 512;
    __syncthreads();

    // online softmax state per head-pair (heads 2w, 2w+1), PV per (hp, ce: dk half)
    float M[2] = {-1e25f, -1e25f};   // > masked bias (-1e30) so all-masked tiles give a=exp(-1e30+1e25)=0
    float L[2] = {0.f, 0.f};
    float PV[2][2] = {{0.f, 0.f}, {0.f, 0.f}};

    for (int nt = 0; nt < 2; ++nt) {
        const int ns = n0 + nt * 64;
        f32x4 acc[4][4] = {};
        // A rows: n = ns + rr*16 + l15 ; k-slice = k0 + lh*8 (per-lane direct from global)
        const float* apb = E + ((size_t)((b * 512 + ns + l15) * 64 + m)) * 256 + lh * 8;
#pragma unroll 2
        for (int k0 = 0; k0 < 256; k0 += 32) {
            bf16x8 af[4];
#pragma unroll
            for (int rr = 0; rr < 4; ++rr) {
                const float* ap = apb + (size_t)rr * (16 * 64 * 256) + k0;
                float4 x0 = *(const float4*)ap;
                float4 x1 = *(const float4*)(ap + 4);
                bf16x8 v;
                v[0] = (__bf16)x0.x; v[1] = (__bf16)x0.y; v[2] = (__bf16)x0.z; v[3] = (__bf16)x0.w;
                v[4] = (__bf16)x1.x; v[5] = (__bf16)x1.y; v[6] = (__bf16)x1.z; v[7] = (__bf16)x1.w;
                af[rr] = v;
            }
#pragma unroll
            for (int c = 0; c < 4; ++c) {
                bf16x8 bv = *(const bf16x8*)(WeT + (size_t)col[c] * 256 + k0 + lh * 8);
#pragma unroll
                for (int rr = 0; rr < 4; ++rr)
                    acc[rr][c] = __builtin_amdgcn_mfma_f32_16x16x32_bf16(af[rr], bv, acc[rr][c], 0, 0, 0);
            }
        }

        // ---- pass 1: per-lane partial scores (2 dk per head per lane) ----
        float s[4][2][4];
#pragma unroll
        for (int rr = 0; rr < 4; ++rr) {
            const int nb = ns + rr * 16 + lh * 4;
#pragma unroll
            for (int r = 0; r < 4; ++r) {
                const size_t krow = (size_t)(nb + r) * 512;
                float p0 = 0.f, p1 = 0.f;
#pragma unroll
                for (int ce = 0; ce < 2; ++ce) {
                    {
                        const int c = ce;          // hp = 0
                        float kf = __bfloat162float(kvb[krow + col[c]]);
                        float ef = acc[rr][c][r] + bev[c];
                        p0 += (qv[c] + ef) * (kf + ef);
                    }
                    {
                        const int c = 2 + ce;      // hp = 1
                        float kf = __bfloat162float(kvb[krow + col[c]]);
                        float ef = acc[rr][c][r] + bev[c];
                        p1 += (qv[c] + ef) * (kf + ef);
                    }
                }
                s[rr][0][r] = p0;
                s[rr][1][r] = p1;
            }
        }
        // ---- butterfly over the 16 dk-lanes -> full 32-dk dot; scale + mask ----
#pragma unroll
        for (int rr = 0; rr < 4; ++rr) {
#pragma unroll
            for (int r = 0; r < 4; ++r) {
                float mb = mbias[nt * 64 + rr * 16 + lh * 4 + r];
#pragma unroll
                for (int hp = 0; hp < 2; ++hp) {
                    float v = s[rr][hp][r];
                    v += __shfl_xor(v, 1);
                    v += __shfl_xor(v, 2);
                    v += __shfl_xor(v, 4);
                    v += __shfl_xor(v, 8);
                    s[rr][hp][r] = v * SCALE + mb;
                }
            }
        }
        // ---- online max update per head ----
#pragma unroll
        for (int hp = 0; hp < 2; ++hp) {
            float tm = s[0][hp][0];
#pragma unroll
            for (int rr = 0; rr < 4; ++rr)
#pragma unroll
                for (int r = 0; r < 4; ++r) tm = fmaxf(tm, s[rr][hp][r]);
            tm = fmaxf(tm, __shfl_xor(tm, 16));
            tm = fmaxf(tm, __shfl_xor(tm, 32));
            float Mn = fmaxf(M[hp], tm);
            float f = __expf(M[hp] - Mn);
            M[hp] = Mn;
            L[hp] *= f;
            PV[hp][0] *= f;
            PV[hp][1] *= f;
        }
        // ---- pass 2: a = exp(s - M); PV += a*(e+v); L += a ----
#pragma unroll
        for (int rr = 0; rr < 4; ++rr) {
            const int nb = ns + rr * 16 + lh * 4;
#pragma unroll
            for (int hp = 0; hp < 2; ++hp) {
#pragma unroll
                for (int r = 0; r < 4; ++r) {
                    const size_t vrow = (size_t)(nb + r) * 512 + 256;
                    float a = __expf(s[rr][hp][r] - M[hp]);
                    L[hp] += a;
                    float ef0 = acc[rr][2 * hp][r]     + bev[2 * hp];
                    float ef1 = acc[rr][2 * hp + 1][r] + bev[2 * hp + 1];
                    float vf0 = __bfloat162float(kvb[vrow + col[2 * hp]]);
                    float vf1 = __bfloat162float(kvb[vrow + col[2 * hp + 1]]);
                    PV[hp][0] += a * (ef0 + vf0);
                    PV[hp][1] += a * (ef1 + vf1);
                }
            }
        }
    }

    // ---- cross-lh reduce (sum over the 4 n-subsets) ----
#pragma unroll
    for (int hp = 0; hp < 2; ++hp) {
        L[hp] += __shfl_xor(L[hp], 16);
        L[hp] += __shfl_xor(L[hp], 32);
#pragma unroll
        for (int ce = 0; ce < 2; ++ce) {
            PV[hp][ce] += __shfl_xor(PV[hp][ce], 16);
            PV[hp][ce] += __shfl_xor(PV[hp][ce], 32);
        }
    }
    const int part = (b * 64 + m) * 4 + qq;
    if (lh == 0) {
#pragma unroll
        for (int hp = 0; hp < 2; ++hp) {
            int h = 2 * w + hp;
#pragma unroll
            for (int ce = 0; ce < 2; ++ce)
                fPV[((size_t)part * 8 + h) * 32 + ce * 16 + l15] = PV[hp][ce];
            if (l15 == 0) {
                fML[((size_t)part * 8 + h) * 2 + 0] = M[hp];
                fML[((size_t)part * 8 + h) * 2 + 1] = L[hp];
            }
        }
    }
}

// ---------------- merge the 4 quarter-partials + self term -> AO ----------------
__global__ __launch_bounds__(256) void flash_merge(const float* __restrict__ fPV,
                                                   const float* __restrict__ fML,
                                                   const __hip_bfloat16* __restrict__ qkvs,
                                                   __hip_bfloat16* __restrict__ AO) {
    const int bm = blockIdx.x;          // b*64 + m
    const int t = threadIdx.x;
    const int h = t >> 5, dk = t & 31;
    const int col = h * 32 + dk;
    const __hip_bfloat16* qb = qkvs + (size_t)bm * 768;
    float qf  = __bfloat162float(qb[col]);
    float ksf = __bfloat162float(qb[256 + col]);
    float p = qf * ksf;
    p += __shfl_xor(p, 1);
    p += __shfl_xor(p, 2);
    p += __shfl_xor(p, 4);
    p += __shfl_xor(p, 8);
    p += __shfl_xor(p, 16);   // xor masks <=16 stay inside the 32-lane head group
    float sself = p * SCALE;
    float Mst = sself;
    float Mq[4], Lq[4], Pq[4];
    const int part0 = bm * 4;
#pragma unroll
    for (int q = 0; q < 4; ++q) {
        Mq[q] = fML[((size_t)(part0 + q) * 8 + h) * 2 + 0];
        Lq[q] = fML[((size_t)(part0 + q) * 8 + h) * 2 + 1];
        Pq[q] = fPV[((size_t)(part0 + q) * 8 + h) * 32 + dk];
        Mst = fmaxf(Mst, Mq[q]);
    }
    float fs = __expf(sself - Mst);
    float Ltot = fs;
    float Ptot = fs * __bfloat162float(qb[512 + col]);
#pragma unroll
    for (int q = 0; q < 4; ++q) {
        float fq = __expf(Mq[q] - Mst);
        Ltot += Lq[q] * fq;
        Ptot += Pq[q] * fq;
    }
    AO[(size_t)bm * 256 + col] = __float2bfloat16(Ptot / Ltot);
}

extern "C" void kernel_launch(void* const* d_in, const int* in_sizes, int n_in,
                              void* d_out, int out_size, void* d_ws, size_t ws_size,
                              hipStream_t stream) {
    const float* machine_emb = (const float*)d_in[0];
    const float* op_emb      = (const float*)d_in[1];
    const float* edge_emb    = (const float*)d_in[2];
    const void*  o2m_mask    = d_in[3];

    char* p = (char*)d_ws;
    int* flags = (int*)p;                        p += 256;
    __hip_bfloat16* WqksvsT = (__hip_bfloat16*)p; p += 196608 * 2;
    __hip_bfloat16* WkvT    = (__hip_bfloat16*)p; p += 131072 * 2;
    __hip_bfloat16* WoT     = (__hip_bfloat16*)p; p += 65536 * 2;
    __hip_bfloat16* WeT     = (__hip_bfloat16*)p; p += 65536 * 2;
    __hip_bfloat16* Wf1T    = (__hip_bfloat16*)p; p += 262144 * 2;
    __hip_bfloat16* Wf2T    = (__hip_bfloat16*)p; p += 262144 * 2;
    float* bqksvs           = (float*)p;          p += 768 * 4;
    float* bkv              = (float*)p;          p += 512 * 4;
    __hip_bfloat16* mnorm   = (__hip_bfloat16*)p; p += 65536 * 2;
    __hip_bfloat16* onorm   = (__hip_bfloat16*)p; p += 524288 * 2;
    __hip_bfloat16* qkvs    = (__hip_bfloat16*)p; p += 196608 * 2;
    __hip_bfloat16* kov     = (__hip_bfloat16*)p; p += 1048576 * 2;
    float* fPV              = (float*)p;          p += 262144 * 4;   // 256*4*8*32
    float* fML              = (float*)p;          p += 16384 * 4;    // 256*4*8*2
    __hip_bfloat16* AO = (__hip_bfloat16*)p;     p += 65536 * 2;
    float* m2        = (float*)p;                p += 65536 * 4;
    __hip_bfloat16* hn = (__hip_bfloat16*)p;     p += 65536 * 2;
    __hip_bfloat16* h1 = (__hip_bfloat16*)p;     p += 262144 * 2;

    // prep: tiled transpose+convert all weights to (N,K) bf16
    TTArgs ta;
    const int srcIdx[9] = {4, 12, 14, 6, 8, 10, 16, 24, 26};
    void* dsts[9] = {WqksvsT, WqksvsT + 65536, WqksvsT + 131072,
                     WkvT, WkvT + 65536, WoT, WeT, Wf1T, Wf2T};
    const int kl9[9] = {8, 8, 8, 8, 8, 8, 8, 8, 10};
    const int nl9[9] = {8, 8, 8, 8, 8, 8, 8, 10, 8};
    int tcum = 0;
    for (int i = 0; i < 9; ++i) {
        ta.src[i] = d_in[srcIdx[i]];
        ta.dst[i] = dsts[i];
        int tiles = (1 << (kl9[i] - 6)) * (1 << (nl9[i] - 6));
        tcum += tiles;
        ta.tcum[i] = tcum;
        ta.kl[i] = kl9[i];
        ta.nl[i] = nl9[i];
    }

    hipLaunchKernelGGL(detect_kernel, dim3(1), dim3(256), 0, stream,
                       (const unsigned int*)o2m_mask, flags);
    hipLaunchKernelGGL(prep_transpose, dim3(tcum), dim3(256), 0, stream, ta);
    hipLaunchKernelGGL(prep_bias, dim3(1), dim3(256), 0, stream,
                       (const float*)d_in[5], (const float*)d_in[13],
                       (const float*)d_in[15], (const float*)d_in[7],
                       (const float*)d_in[9], bqksvs, bkv);

    // LayerNorms (fp32 in -> bf16 out)
    hipLaunchKernelGGL(ln_kernel, dim3(256), dim3(256), 0, stream,
                       machine_emb, (const float*)d_in[18], (const float*)d_in[19], mnorm);
    hipLaunchKernelGGL(ln_kernel, dim3(2048), dim3(256), 0, stream,
                       op_emb, (const float*)d_in[22], (const float*)d_in[23], onorm);

    // projections (MFMA)
    hipLaunchKernelGGL(gemm64, dim3(4, 12), dim3(256), 0, stream,
                       mnorm, WqksvsT, bqksvs, nullptr, qkvs, 256, 768, 0);
    hipLaunchKernelGGL(gemm64, dim3(32, 8), dim3(256), 0, stream,
                       onorm, WkvT, bkv, nullptr, kov, 256, 512, 0);

    // fused flash-style edge GEMM + masked scores + online softmax + PV partials
    hipLaunchKernelGGL(edge_flash, dim3(1024), dim3(256), 0, stream,
                       edge_emb, WeT, (const float*)d_in[17],
                       qkvs, kov, o2m_mask, flags, fPV, fML);

    // merge quarter partials + self term -> AO
    hipLaunchKernelGGL(flash_merge, dim3(256), dim3(256), 0, stream,
                       fPV, fML, qkvs, AO);

    // out proj + residual -> m2 (f32), LN2, FFN
    hipLaunchKernelGGL(gemm64, dim3(4, 4), dim3(256), 0, stream,
                       AO, WoT, (const float*)d_in[11], machine_emb, m2, 256, 256, 4 | 8);
    hipLaunchKernelGGL(ln_kernel, dim3(256), dim3(256), 0, stream,
                       m2, (const float*)d_in[20], (const float*)d_in[21], hn);
    hipLaunchKernelGGL(gemm64, dim3(4, 16), dim3(256), 0, stream,
                       hn, Wf1T, (const float*)d_in[25], nullptr, h1, 256, 1024, 1);
    hipLaunchKernelGGL(gemm64, dim3(4, 4), dim3(256), 0, stream,
                       h1, Wf2T, (const float*)d_in[27], m2, (float*)d_out, 1024, 256, 4 | 8);
}

// Round 4
// 356.152 us; speedup vs baseline: 1.1363x; 1.1363x over previous
//
#include <hip/hip_runtime.h>
#include <hip/hip_bf16.h>
#include <math.h>

#define H_ 8
#define DK_ 32
#define B_ 4
#define M_ 64
#define N_ 512
#define D_ 256
#define F_ 1024

static constexpr float SCALE = 0.17677669529663687f; // 1/sqrt(32)
static constexpr float EPS = 1e-5f;

typedef __bf16 bf16x8 __attribute__((ext_vector_type(8)));
typedef float f32x4 __attribute__((ext_vector_type(4)));

__device__ inline float bfbits2f(unsigned int b) {
    union { unsigned int i; float f; } c; c.i = b << 16; return c.f;
}
__device__ inline void unpack8(uint4 u, float* f) {
    f[0] = bfbits2f(u.x & 0xffffu); f[1] = bfbits2f(u.x >> 16);
    f[2] = bfbits2f(u.y & 0xffffu); f[3] = bfbits2f(u.y >> 16);
    f[4] = bfbits2f(u.z & 0xffffu); f[5] = bfbits2f(u.z >> 16);
    f[6] = bfbits2f(u.w & 0xffffu); f[7] = bfbits2f(u.w >> 16);
}

// ---------------- prep: weight transpose tiles + (last block) bias concat + flag init ----
struct TTArgs {
    const void* src[9];
    void* dst[9];
    int tcum[9];   // cumulative 64x64 tile counts
    int kl[9];     // log2 K
    int nl[9];     // log2 N
    const float* bq; const float* bks; const float* bvs; const float* bk; const float* bv;
    float* bqksvs; float* bkv; int* flags;
};

__global__ __launch_bounds__(256) void prep_all(TTArgs a) {
    __shared__ float ld[64][65];
    int bx = blockIdx.x;
    int t = threadIdx.x;
    if (bx >= a.tcum[8]) {          // bias + flag-init block
        a.bqksvs[t] = a.bq[t];
        a.bqksvs[256 + t] = a.bks[t];
        a.bqksvs[512 + t] = a.bvs[t];
        a.bkv[t] = a.bk[t];
        a.bkv[256 + t] = a.bv[t];
        if (t == 0) a.flags[1] = 0;
        return;
    }
    int ti = 0;
    while (bx >= a.tcum[ti]) ti++;
    int j = bx - (ti ? a.tcum[ti - 1] : 0);
    int K = 1 << a.kl[ti], N = 1 << a.nl[ti];
    int ntn = N >> 6;
    int kt = j / ntn, nt = j - kt * ntn;
    const float* src = (const float*)a.src[ti];
    __hip_bfloat16* dst = (__hip_bfloat16*)a.dst[ti];
    int col = t & 63, r0 = t >> 6;
#pragma unroll
    for (int i = 0; i < 16; ++i) {
        int r = i * 4 + r0;
        ld[r][col] = src[(size_t)(kt * 64 + r) * N + nt * 64 + col];
    }
    __syncthreads();
#pragma unroll
    for (int i = 0; i < 16; ++i) {
        int r = i * 4 + r0;
        dst[(size_t)(nt * 64 + r) * K + kt * 64 + col] = __float2bfloat16(ld[col][r]);
    }
}

// ---------------- block reduce (256 threads = 4 waves) ----------------
__device__ inline float block_reduce256(float v, bool is_max, float* sbuf) {
#pragma unroll
    for (int off = 32; off > 0; off >>= 1) {
        float o = __shfl_down(v, off, 64);
        v = is_max ? fmaxf(v, o) : (v + o);
    }
    int lane = threadIdx.x & 63, wid = threadIdx.x >> 6;
    if (lane == 0) sbuf[wid] = v;
    __syncthreads();
    float r;
    if (is_max) r = fmaxf(fmaxf(sbuf[0], sbuf[1]), fmaxf(sbuf[2], sbuf[3]));
    else        r = sbuf[0] + sbuf[1] + sbuf[2] + sbuf[3];
    __syncthreads();
    return r;
}

// ---------------- fused: both LayerNorms + parallel mask-dtype detect ----------------
// blocks 0..255: machine LN; 256..2303: op LN; 2304..2335: detect (atomicOr into flags[1])
__global__ __launch_bounds__(256) void ln_detect(const float* __restrict__ me,
                                                 const float* __restrict__ oe,
                                                 const float* __restrict__ g1v,
                                                 const float* __restrict__ b1v,
                                                 const float* __restrict__ gov,
                                                 const float* __restrict__ bov,
                                                 __hip_bfloat16* __restrict__ mnorm,
                                                 __hip_bfloat16* __restrict__ onorm,
                                                 const unsigned int* __restrict__ mask,
                                                 int* __restrict__ flags) {
    __shared__ float sbuf[4];
    int bx = blockIdx.x, t = threadIdx.x;
    if (bx >= 2304) {
        // scan first 128 KB of mask as uints (valid for both u8 and i32 layouts)
        uint4 v = ((const uint4*)mask)[(size_t)(bx - 2304) * 256 + t];
        if (v.x > 1u || v.y > 1u || v.z > 1u || v.w > 1u) atomicOr(flags + 1, 1);
        return;
    }
    const float* xin; const float* g; const float* bta; __hip_bfloat16* out; int row;
    if (bx < 256) { xin = me; g = g1v; bta = b1v; out = mnorm; row = bx; }
    else          { xin = oe; g = gov; bta = bov; out = onorm; row = bx - 256; }
    size_t idx = (size_t)row * 256 + t;
    float x = xin[idx];
    float s  = block_reduce256(x, false, sbuf);
    float ss = block_reduce256(x * x, false, sbuf);
    float mu = s * (1.f / 256.f);
    float var = ss * (1.f / 256.f) - mu * mu;
    float y = (x - mu) * rsqrtf(var + EPS) * g[t] + bta[t];
    out[idx] = __float2bfloat16(y);
}

// ---------------- LayerNorm: fp32 in -> bf16 out (back half) ----------------
__global__ __launch_bounds__(256) void ln_kernel(const float* __restrict__ xin,
                                                 const float* __restrict__ g,
                                                 const float* __restrict__ bta,
                                                 __hip_bfloat16* __restrict__ out) {
    __shared__ float sbuf[4];
    int row = blockIdx.x, d = threadIdx.x;
    size_t idx = (size_t)row * 256 + d;
    float x = xin[idx];
    float s  = block_reduce256(x, false, sbuf);
    float ss = block_reduce256(x * x, false, sbuf);
    float mu = s * (1.f / 256.f);
    float var = ss * (1.f / 256.f) - mu * mu;
    float y = (x - mu) * rsqrtf(var + EPS) * g[d] + bta[d];
    out[idx] = __float2bfloat16(y);
}

// ---------------- generic MFMA GEMM: out(M,ldc) = A(M,K) @ BT(N,K)^T + bias ----------------
// flags: 1=relu, 4=resid f32, 8=out f32 (else bf16)
__global__ __launch_bounds__(256) void gemm64(const __hip_bfloat16* __restrict__ A,
                                              const __hip_bfloat16* __restrict__ BT,
                                              const float* __restrict__ bias,
                                              const float* __restrict__ resid,
                                              void* __restrict__ out,
                                              int K, int ldc, int flags) {
    __shared__ __align__(16) __bf16 As[64 * 40];
    __shared__ __align__(16) __bf16 Bs[64 * 40];
    const int rowBase = blockIdx.x * 64;
    const int colBase = blockIdx.y * 64;
    const int t = threadIdx.x;
    const int w = t >> 6;
    const int l = t & 63;
    const int lrow = l & 15;
    const int lk8 = (l >> 4) * 8;
    const int ar = t >> 2;
    const int ac = (t & 3) * 8;

    f32x4 acc[4] = {};
    for (int k0 = 0; k0 < K; k0 += 32) {
        bf16x8 av = *(const bf16x8*)(A + (size_t)(rowBase + ar) * K + k0 + ac);
        bf16x8 bv = *(const bf16x8*)(BT + (size_t)(colBase + ar) * K + k0 + ac);
        __syncthreads();
        *(bf16x8*)(As + ar * 40 + ac) = av;
        *(bf16x8*)(Bs + ar * 40 + ac) = bv;
        __syncthreads();
        bf16x8 af = *(const bf16x8*)(As + (w * 16 + lrow) * 40 + lk8);
#pragma unroll
        for (int c = 0; c < 4; ++c) {
            bf16x8 bf = *(const bf16x8*)(Bs + (c * 16 + lrow) * 40 + lk8);
            acc[c] = __builtin_amdgcn_mfma_f32_16x16x32_bf16(af, bf, acc[c], 0, 0, 0);
        }
    }
    int rbase = rowBase + w * 16 + ((l >> 4) * 4);
#pragma unroll
    for (int c = 0; c < 4; ++c) {
        int col = colBase + c * 16 + (l & 15);
        float bb = bias[col];
#pragma unroll
        for (int r = 0; r < 4; ++r) {
            int row = rbase + r;
            size_t oi = (size_t)row * ldc + col;
            float v = acc[c][r] + bb;
            if (flags & 1) v = fmaxf(v, 0.f);
            if (flags & 4) v += resid[oi];
            if (flags & 8) ((float*)out)[oi] = v;
            else ((__hip_bfloat16*)out)[oi] = __float2bfloat16(v);
        }
    }
}

// ---------------- dual GEMM: qkvs (48 blocks) + kov (256 blocks) in one launch ----------
__global__ __launch_bounds__(256) void gemm64_dual(const __hip_bfloat16* __restrict__ A0,
                                                   const __hip_bfloat16* __restrict__ BT0,
                                                   const float* __restrict__ bias0,
                                                   __hip_bfloat16* __restrict__ out0,
                                                   const __hip_bfloat16* __restrict__ A1,
                                                   const __hip_bfloat16* __restrict__ BT1,
                                                   const float* __restrict__ bias1,
                                                   __hip_bfloat16* __restrict__ out1) {
    __shared__ __align__(16) __bf16 As[64 * 40];
    __shared__ __align__(16) __bf16 Bs[64 * 40];
    const int id = blockIdx.x;
    const __hip_bfloat16* A; const __hip_bfloat16* BT; const float* bias;
    __hip_bfloat16* out; int bx, by, ldc;
    if (id < 48) { A = A0; BT = BT0; bias = bias0; out = out0; bx = id & 3;  by = id >> 2; ldc = 768; }
    else { int j = id - 48; A = A1; BT = BT1; bias = bias1; out = out1; bx = j & 31; by = j >> 5; ldc = 512; }
    const int rowBase = bx * 64;
    const int colBase = by * 64;
    const int t = threadIdx.x;
    const int w = t >> 6;
    const int l = t & 63;
    const int lrow = l & 15;
    const int lk8 = (l >> 4) * 8;
    const int ar = t >> 2;
    const int ac = (t & 3) * 8;

    f32x4 acc[4] = {};
    for (int k0 = 0; k0 < 256; k0 += 32) {
        bf16x8 av = *(const bf16x8*)(A + (size_t)(rowBase + ar) * 256 + k0 + ac);
        bf16x8 bv = *(const bf16x8*)(BT + (size_t)(colBase + ar) * 256 + k0 + ac);
        __syncthreads();
        *(bf16x8*)(As + ar * 40 + ac) = av;
        *(bf16x8*)(Bs + ar * 40 + ac) = bv;
        __syncthreads();
        bf16x8 af = *(const bf16x8*)(As + (w * 16 + lrow) * 40 + lk8);
#pragma unroll
        for (int c = 0; c < 4; ++c) {
            bf16x8 bf = *(const bf16x8*)(Bs + (c * 16 + lrow) * 40 + lk8);
            acc[c] = __builtin_amdgcn_mfma_f32_16x16x32_bf16(af, bf, acc[c], 0, 0, 0);
        }
    }
    int rbase = rowBase + w * 16 + ((l >> 4) * 4);
#pragma unroll
    for (int c = 0; c < 4; ++c) {
        int col = colBase + c * 16 + (l & 15);
        float bb = bias[col];
#pragma unroll
        for (int r = 0; r < 4; ++r) {
            int row = rbase + r;
            out[(size_t)row * ldc + col] = __float2bfloat16(acc[c][r] + bb);
        }
    }
}

// ---------------- edge GEMM v4: one block per (b,n). A staged in padded LDS,
// B direct from L1-resident WeT. Fused eperm store + masked scores written
// DIRECTLY in (b,h,m,n) layout (scattered 4B stores, L2-absorbed). --------
__global__ __launch_bounds__(256) void edge_gemm4(const float* __restrict__ E,
                                                  const __hip_bfloat16* __restrict__ WeT,
                                                  const float* __restrict__ be,
                                                  const __hip_bfloat16* __restrict__ qkvs,
                                                  const __hip_bfloat16* __restrict__ kov,
                                                  const void* __restrict__ mask,
                                                  const int* __restrict__ flags,
                                                  __hip_bfloat16* __restrict__ eperm,
                                                  float* __restrict__ scT) {
    __shared__ __align__(16) __bf16 smem[64 * 272];   // 34816 B
    __bf16* As = smem;                                // 64 x 40 (K-loop)
    __bf16* Cs = smem;                                // 64 x 272 (epilogue)
    const int bn = blockIdx.x;               // b*512 + n
    const int b = bn >> 9, n = bn & 511;
    const int t = threadIdx.x;
    const int w = t >> 6;
    const int l = t & 63;
    const int lrow = l & 15;
    const int lk8 = (l >> 4) * 8;
    const int ar = t >> 2;
    const int ac = (t & 3) * 8;
    const float* Ab = E + (size_t)bn * 64 * 256;

    f32x4 acc[4][4] = {};
    for (int k0 = 0; k0 < 256; k0 += 32) {
        const float* ap = Ab + (size_t)ar * 256 + k0 + ac;
        float4 x0 = *(const float4*)ap;
        float4 x1 = *(const float4*)(ap + 4);
        bf16x8 av;
        av[0] = (__bf16)x0.x; av[1] = (__bf16)x0.y; av[2] = (__bf16)x0.z; av[3] = (__bf16)x0.w;
        av[4] = (__bf16)x1.x; av[5] = (__bf16)x1.y; av[6] = (__bf16)x1.z; av[7] = (__bf16)x1.w;
        __syncthreads();
        *(bf16x8*)(As + ar * 40 + ac) = av;
        __syncthreads();
        bf16x8 af[4];
#pragma unroll
        for (int rr = 0; rr < 4; ++rr)
            af[rr] = *(const bf16x8*)(As + (rr * 16 + lrow) * 40 + lk8);
#pragma unroll
        for (int c = 0; c < 4; ++c) {
            bf16x8 bf = *(const bf16x8*)(WeT + (size_t)(w * 64 + c * 16 + lrow) * 256 + k0 + lk8);
#pragma unroll
            for (int rr = 0; rr < 4; ++rr)
                acc[rr][c] = __builtin_amdgcn_mfma_f32_16x16x32_bf16(af[rr], bf, acc[rr][c], 0, 0, 0);
        }
    }
    __syncthreads();
    // epilogue: stage C (64 m x 256 d) with bias in LDS
#pragma unroll
    for (int c = 0; c < 4; ++c) {
        int col = w * 64 + c * 16 + (l & 15);
        float bb = be[col];
#pragma unroll
        for (int rr = 0; rr < 4; ++rr) {
#pragma unroll
            for (int r = 0; r < 4; ++r) {
                int m = rr * 16 + (l >> 4) * 4 + r;
                Cs[m * 272 + col] = (__bf16)(acc[rr][c][r] + bb);
            }
        }
    }
    __syncthreads();
    const bool u8 = flags[1] != 0;
    const int seg = t & 31;
    const int h = seg >> 2;
    const int dk8 = (seg & 3) * 8;
#pragma unroll
    for (int j = 0; j < 8; ++j) {
        int m = j * 8 + (t >> 5);
        uint4 ev4 = *(const uint4*)(Cs + m * 272 + seg * 8);
        // eperm store (coalesced 64B runs)
        size_t bhm = (size_t)((b * 8 + h) * 64 + m);
        *(uint4*)(eperm + (bhm * 512 + n) * 32 + dk8) = ev4;
        // fused score partial: sum_dk (q+e)(k+e) over this thread's 8 dk
        float ev[8], qf[8], kf[8];
        unpack8(ev4, ev);
        uint4 qv4 = *(const uint4*)(qkvs + (size_t)(b * 64 + m) * 768 + h * 32 + dk8);
        uint4 kv4 = *(const uint4*)(kov + (size_t)(b * 512 + n) * 512 + h * 32 + dk8);
        unpack8(qv4, qf);
        unpack8(kv4, kf);
        float p = 0.f;
#pragma unroll
        for (int i = 0; i < 8; ++i)
            p += (qf[i] + ev[i]) * (kf[i] + ev[i]);
        p += __shfl_xor(p, 1, 64);
        p += __shfl_xor(p, 2, 64);
        if ((t & 3) == 0) {
            int mi = (b * 512 + n) * 64 + m;
            int mk = u8 ? (int)((const unsigned char*)mask)[mi] : ((const int*)mask)[mi];
            // direct (b,h,m,n) layout: kills the separate transpose kernel
            scT[(bhm << 9) + n] = mk ? p * SCALE : -__builtin_inff();
        }
    }
}

// ---------------- fused softmax + attn output: one block per (b,h,m) ----------------
__global__ __launch_bounds__(256) void smax_attnout(const float* __restrict__ sc,
                                                    const __hip_bfloat16* __restrict__ qkvs,
                                                    const __hip_bfloat16* __restrict__ kov,
                                                    const __hip_bfloat16* __restrict__ eperm,
                                                    __hip_bfloat16* __restrict__ AO) {
    __shared__ float sbuf[4];
    __shared__ float attnS[512];
    __shared__ float selfSc;
    __shared__ float selfA;
    __shared__ float red[16][8];
    int bhm = blockIdx.x;
    int m = bhm & 63;
    int h = (bhm >> 6) & 7;
    int b = bhm >> 9;
    int t = threadIdx.x;
    if (t == 0) {
        const __hip_bfloat16* q  = qkvs + (size_t)(b * 64 + m) * 768 + h * 32;
        const __hip_bfloat16* ks = q + 256;
        float s = 0.f;
        for (int i = 0; i < 32; ++i) s += __bfloat162float(q[i]) * __bfloat162float(ks[i]);
        selfSc = s * SCALE;
    }
    __syncthreads();
    float sv = selfSc;
    float s0 = sc[(size_t)bhm * 512 + t];
    float s1 = sc[(size_t)bhm * 512 + 256 + t];
    float mx = block_reduce256(fmaxf(fmaxf(s0, s1), sv), true, sbuf);
    float e0 = __expf(s0 - mx);
    float e1 = __expf(s1 - mx);
    float eself = __expf(sv - mx);
    float sum = block_reduce256(e0 + e1 + (t == 0 ? eself : 0.f), false, sbuf);
    float inv = 1.f / sum;
    attnS[t] = e0 * inv;
    attnS[256 + t] = e1 * inv;
    if (t == 0) selfA = eself * inv;
    __syncthreads();

    // attn @ (V+E): thread (d8=(t&3)*8, ng=t>>2), 8 n-iters
    const int d8 = (t & 3) * 8;
    const int ng = t >> 2;
    const int w = t >> 6, l = t & 63;
    const __hip_bfloat16* ebase = eperm + (size_t)bhm * 512 * 32;
    const __hip_bfloat16* vbase = kov + (size_t)(b * 512) * 512 + 256 + h * 32;
    float accv[8] = {};
#pragma unroll
    for (int i = 0; i < 8; ++i) {
        int n = ng + i * 64;
        float a = attnS[n];
        float ev[8], vv[8];
        uint4 e4 = *(const uint4*)(ebase + (size_t)n * 32 + d8);
        uint4 v4 = *(const uint4*)(vbase + (size_t)n * 512 + d8);
        unpack8(e4, ev);
        unpack8(v4, vv);
#pragma unroll
        for (int k = 0; k < 8; ++k) accv[k] += a * (vv[k] + ev[k]);
    }
#pragma unroll
    for (int off = 4; off <= 32; off <<= 1) {
#pragma unroll
        for (int k = 0; k < 8; ++k) accv[k] += __shfl_xor(accv[k], off, 64);
    }
    if ((l >> 2) == 0) {
#pragma unroll
        for (int k = 0; k < 8; ++k) red[w * 4 + (l & 3)][k] = accv[k];
    }
    __syncthreads();
    if (t < 32) {
        int slot = t >> 3, elem = t & 7;
        float r = red[slot][elem] + red[4 + slot][elem] + red[8 + slot][elem] + red[12 + slot][elem];
        float vs = __bfloat162float(qkvs[(size_t)(b * 64 + m) * 768 + 512 + h * 32 + t]);
        r += selfA * vs;
        AO[(size_t)(b * 64 + m) * 256 + h * 32 + t] = __float2bfloat16(r);
    }
}

extern "C" void kernel_launch(void* const* d_in, const int* in_sizes, int n_in,
                              void* d_out, int out_size, void* d_ws, size_t ws_size,
                              hipStream_t stream) {
    const float* machine_emb = (const float*)d_in[0];
    const float* op_emb      = (const float*)d_in[1];
    const float* edge_emb    = (const float*)d_in[2];
    const void*  o2m_mask    = d_in[3];

    char* p = (char*)d_ws;
    int* flags = (int*)p;                        p += 256;
    __hip_bfloat16* WqksvsT = (__hip_bfloat16*)p; p += 196608 * 2;
    __hip_bfloat16* WkvT    = (__hip_bfloat16*)p; p += 131072 * 2;
    __hip_bfloat16* WoT     = (__hip_bfloat16*)p; p += 65536 * 2;
    __hip_bfloat16* WeT     = (__hip_bfloat16*)p; p += 65536 * 2;
    __hip_bfloat16* Wf1T    = (__hip_bfloat16*)p; p += 262144 * 2;
    __hip_bfloat16* Wf2T    = (__hip_bfloat16*)p; p += 262144 * 2;
    float* bqksvs           = (float*)p;          p += 768 * 4;
    float* bkv              = (float*)p;          p += 512 * 4;
    __hip_bfloat16* mnorm   = (__hip_bfloat16*)p; p += 65536 * 2;
    __hip_bfloat16* onorm   = (__hip_bfloat16*)p; p += 524288 * 2;
    __hip_bfloat16* qkvs    = (__hip_bfloat16*)p; p += 196608 * 2;
    __hip_bfloat16* kov     = (__hip_bfloat16*)p; p += 1048576 * 2;
    __hip_bfloat16* eperm   = (__hip_bfloat16*)p; p += (size_t)33554432 * 2;
    float* scT       = (float*)p;                p += (size_t)1048576 * 4;
    __hip_bfloat16* AO = (__hip_bfloat16*)p;     p += 65536 * 2;
    float* m2        = (float*)p;                p += 65536 * 4;
    __hip_bfloat16* hn = (__hip_bfloat16*)p;     p += 65536 * 2;
    __hip_bfloat16* h1 = (__hip_bfloat16*)p;     p += 262144 * 2;

    // prep: tiled transpose+convert all weights to (N,K) bf16 + bias concat + flag init
    TTArgs ta;
    const int srcIdx[9] = {4, 12, 14, 6, 8, 10, 16, 24, 26};
    void* dsts[9] = {WqksvsT, WqksvsT + 65536, WqksvsT + 131072,
                     WkvT, WkvT + 65536, WoT, WeT, Wf1T, Wf2T};
    const int kl9[9] = {8, 8, 8, 8, 8, 8, 8, 8, 10};
    const int nl9[9] = {8, 8, 8, 8, 8, 8, 8, 10, 8};
    int tcum = 0;
    for (int i = 0; i < 9; ++i) {
        ta.src[i] = d_in[srcIdx[i]];
        ta.dst[i] = dsts[i];
        int tiles = (1 << (kl9[i] - 6)) * (1 << (nl9[i] - 6));
        tcum += tiles;
        ta.tcum[i] = tcum;
        ta.kl[i] = kl9[i];
        ta.nl[i] = nl9[i];
    }
    ta.bq = (const float*)d_in[5];  ta.bks = (const float*)d_in[13];
    ta.bvs = (const float*)d_in[15]; ta.bk = (const float*)d_in[7];
    ta.bv = (const float*)d_in[9];
    ta.bqksvs = bqksvs; ta.bkv = bkv; ta.flags = flags;

    hipLaunchKernelGGL(prep_all, dim3(tcum + 1), dim3(256), 0, stream, ta);

    // LayerNorms (both) + parallel mask detect
    hipLaunchKernelGGL(ln_detect, dim3(2336), dim3(256), 0, stream,
                       machine_emb, op_emb,
                       (const float*)d_in[18], (const float*)d_in[19],
                       (const float*)d_in[22], (const float*)d_in[23],
                       mnorm, onorm, (const unsigned int*)o2m_mask, flags);

    // projections (qkvs + kov in one launch)
    hipLaunchKernelGGL(gemm64_dual, dim3(304), dim3(256), 0, stream,
                       mnorm, WqksvsT, bqksvs, qkvs,
                       onorm, WkvT, bkv, kov);

    // edge GEMM + fused eperm store + fused masked scores (direct b,h,m,n layout)
    hipLaunchKernelGGL(edge_gemm4, dim3(2048), dim3(256), 0, stream,
                       edge_emb, WeT, (const float*)d_in[17],
                       qkvs, kov, o2m_mask, flags, eperm, scT);

    // fused softmax + attn output
    hipLaunchKernelGGL(smax_attnout, dim3(2048), dim3(256), 0, stream,
                       scT, qkvs, kov, eperm, AO);

    // out proj + residual -> m2 (f32), LN2, FFN
    hipLaunchKernelGGL(gemm64, dim3(4, 4), dim3(256), 0, stream,
                       AO, WoT, (const float*)d_in[11], machine_emb, m2, 256, 256, 4 | 8);
    hipLaunchKernelGGL(ln_kernel, dim3(256), dim3(256), 0, stream,
                       m2, (const float*)d_in[20], (const float*)d_in[21], hn);
    hipLaunchKernelGGL(gemm64, dim3(4, 16), dim3(256), 0, stream,
                       hn, Wf1T, (const float*)d_in[25], nullptr, h1, 256, 1024, 1);
    hipLaunchKernelGGL(gemm64, dim3(4, 4), dim3(256), 0, stream,
                       h1, Wf2T, (const float*)d_in[27], m2, (float*)d_out, 1024, 256, 4 | 8);
}